// Round 2
// baseline (552.070 us; speedup 1.0000x reference)
//
#include <hip/hip_runtime.h>

#define N_ATOM 30000
#define N_PAIR 1000000
#define N_TRI  4000000
#define N_SF   16
#define FP_ELEMS (N_ATOM * N_SF)

#define ASH  5                      // atoms per coarse bucket = 32
#define APB  32
#define NCB  938                    // ceil(30000/32)
#define NSUB 8                      // XCD sub-buckets (bin3 scatter spreading)
#define NSEG (NCB * NSUB)           // 7504
#define OVF_CNT_IDX NSEG
#define OVF_CAP 131072
#define TILE 4096
#define PER_TH 16
#define NTILES ((N_TRI + TILE - 1) / TILE)   // 977
#define WCAP 1280                   // LDS window cap (bucket pairs ~1067 +- 33)
#define MERGE 4                     // subs merged per reduce4 block
#define NRB (NCB * 2)               // reduce4 grid: one block per bucket-half

// workspace layout (bytes)
// [0, 167936) zeroed by zero_meta (ccnt + pcnt + pplace + pbase); flagbits too
#define OFF_CCNT   0ULL             // (NSEG+1) ints (reserve 32 KiB)
#define OFF_PCNT   32768ULL         // 938 counters, padded stride 16 ints
#define OFF_PPLACE 98304ULL         // 938 counters, padded stride 16 ints
#define OFF_PBASE  163840ULL        // 939 ints (exclusive bases + sentinel)
#define OFF_AMAP   196608ULL        // 4,000,000 B: per-pair {c:10|a5:5|lidx:17}
#define OFF_FLAGB  4196608ULL       // 131,072 B: ij-valid bit per permuted pair
#define OFF_OVF    4327680ULL       // 1,048,576 B: int2 * 131072
#define OFF_PACKS  5376256ULL       // 16,000,000 B: float4 {dx,dy,dz, bitcast(ikmax)}
#define OFF_CB     21376256ULL      // cbucket: NSEG * cap * 8
#define ZERO_INTS  41984            // 167,936 / 4
#define FLAGB_INTS 32768

__device__ __constant__ float c_eta[16] = {
    0.01f, 0.014f, 0.02f, 0.028f, 0.04f, 0.056f, 0.08f, 0.11f,
    0.16f, 0.22f, 0.32f, 0.45f, 0.63f, 0.72f, 0.9f, 1.0f};

// ---------------------------------------------------------------------------
// geometry math; fc recomputed from distances (pack.w carries the ik max)
__device__ __forceinline__ bool tri_math(
    float4 A, float4 B, float A8[8], float& R2)
{
    float ax = A.x, ay = A.y, az = A.z;
    float bx = B.x, by = B.y, bz = B.z;
    float d2ij = fmaf(ax, ax, fmaf(ay, ay, az * az));
    float d2ik = fmaf(bx, bx, fmaf(by, by, bz * bz));
    float jx = bx - ax, jy = by - ay, jz = bz - az;
    float d2jk = fmaf(jx, jx, fmaf(jy, jy, jz * jz));
    if (!(d2jk < 36.0f)) return false;
    float dij = sqrtf(d2ij);
    float dik = sqrtf(d2ik);
    float djk = sqrtf(d2jk);
    const float PI_OVER_RC = 0.5235987755982988f;
    float fcij = 0.5f * (__cosf(PI_OVER_RC * dij) + 1.0f);
    float fcik = 0.5f * (__cosf(PI_OVER_RC * dik) + 1.0f);
    float fcjk = 0.5f * (__cosf(PI_OVER_RC * djk) + 1.0f);
    float dot = fmaf(ax, bx, fmaf(ay, by, az * bz));
    float cosv = dot / (dij * dik);
    R2 = d2ij + d2ik + d2jk;
    float FCt = fcij * fcik * fcjk;
    float bm = fmaxf(1.0f - cosv, 0.0f);
    float bp = fmaxf(1.0f + cosv, 0.0f);
    float bm2 = bm * bm, bp2 = bp * bp;
    float bm4 = bm2 * bm2, bp4 = bp2 * bp2;
    float bm8 = bm4 * bm4, bp8 = bp4 * bp4;
    A8[0] = FCt * bm;               A8[1] = FCt * bp;
    A8[2] = 0.5f * FCt * bm2;       A8[3] = 0.5f * FCt * bp2;
    A8[4] = 0.125f * FCt * bm4;     A8[5] = 0.125f * FCt * bp4;
    A8[6] = 0.0078125f * FCt * bm8; A8[7] = 0.0078125f * FCt * bp8;
    return true;
}

// ---------------------------------------------------------------------------
// fast path
// ---------------------------------------------------------------------------

__global__ __launch_bounds__(256) void zero_meta(
    int* __restrict__ m, unsigned int* __restrict__ fb)
{
    int i = blockIdx.x * blockDim.x + threadIdx.x;
    if (i < ZERO_INTS) m[i] = 0;
    if (i < FLAGB_INTS) fb[i] = 0u;
}

// histogram pairs per coarse bucket (LDS-staged; padded global counters)
__global__ __launch_bounds__(256) void pair_hist(
    const int2* __restrict__ ind2, int* __restrict__ pcnt)
{
    __shared__ int h[NCB];
    for (int i = threadIdx.x; i < NCB; i += 256) h[i] = 0;
    __syncthreads();
    int stride = gridDim.x * 256;
    for (int p = blockIdx.x * 256 + threadIdx.x; p < N_PAIR; p += stride)
        atomicAdd(&h[ind2[p].x >> ASH], 1);
    __syncthreads();
    for (int i = threadIdx.x; i < NCB; i += 256) {
        int v = h[i];
        if (v) atomicAdd(&pcnt[i * 16], v);
    }
}

// exclusive prefix scan of the 938 bucket counts (single 1024-thread block)
__global__ __launch_bounds__(1024) void scan_bases(
    const int* __restrict__ pcnt, int* __restrict__ pbase)
{
    __shared__ int s[1024];
    int t = threadIdx.x;
    int v0 = (t < NCB) ? pcnt[t * 16] : 0;
    s[t] = v0;
    __syncthreads();
    for (int off = 1; off < 1024; off <<= 1) {
        int v = 0;
        if (t >= off) v = s[t - off];
        __syncthreads();
        s[t] += v;
        __syncthreads();
    }
    if (t < NCB) pbase[t] = s[t] - v0;     // exclusive
    if (t == 0) pbase[NCB] = N_PAIR;       // sentinel
}

// place pairs into bucket-permuted packs[] (w = bitcast(-1) running max);
// build amap; also zero the fp output rows
__global__ __launch_bounds__(256) void pair_place(
    const int2* __restrict__ ind2, const float* __restrict__ diff,
    const int* __restrict__ pbase, int* __restrict__ pplace,
    unsigned int* __restrict__ amap, float4* __restrict__ packs,
    float* __restrict__ out)
{
    int p = blockIdx.x * blockDim.x + threadIdx.x;
    if (p < FP_ELEMS) out[p] = 0.0f;
    if (p >= N_PAIR) return;
    int a = ind2[p].x;
    int c = a >> ASH;
    int l = atomicAdd(&pplace[c * 16], 1);
    int q = pbase[c] + l;
    amap[p] = ((unsigned)c << 22) | ((unsigned)(a & (APB - 1)) << 17) | (unsigned)l;
    float4 r;
    r.x = diff[3 * p + 0];
    r.y = diff[3 * p + 1];
    r.z = diff[3 * p + 2];
    r.w = __int_as_float(-1);
    packs[q] = r;
}

// LDS-staged counting scatter into coarse buckets (XCD sub-bucketed).
// Entries carry {a5,lidx} for the ij side and the permuted index q for ik.
__global__ __launch_bounds__(256) void bin3(
    const int2* __restrict__ ind3, const unsigned int* __restrict__ amap,
    const int* __restrict__ pbase,
    int* __restrict__ ccnt, int2* __restrict__ cbucket,
    int2* __restrict__ ovf, int cap)
{
    __shared__ int lcnt[NCB];
    __shared__ int lbase[NCB];
    const int thr = threadIdx.x;
    const int sub = blockIdx.x & (NSUB - 1);
    const long long t0 = (long long)blockIdx.x * TILE;

    for (int i = thr; i < NCB; i += 256) lcnt[i] = 0;
    __syncthreads();

    unsigned int mij_r[PER_TH];
    int qik_r[PER_TH];
    int slot_r[PER_TH];
#pragma unroll
    for (int j = 0; j < PER_TH; ++j) {
        long long t = t0 + j * 256 + thr;
        unsigned int mij = 0; int qik = 0, s = -1;
        if (t < N_TRI) {
            int2 pr = ind3[t];
            mij = amap[pr.x];
            unsigned int mik = amap[pr.y];
            qik = pbase[mik >> 22] + (int)(mik & 0x1FFFF);
            s = atomicAdd(&lcnt[mij >> 22], 1);
        }
        mij_r[j] = mij; qik_r[j] = qik; slot_r[j] = s;
    }
    __syncthreads();
    for (int c = thr; c < NCB; c += 256) {
        int n = lcnt[c];
        lbase[c] = n ? atomicAdd(&ccnt[c * NSUB + sub], n) : 0;
    }
    __syncthreads();
#pragma unroll
    for (int j = 0; j < PER_TH; ++j) {
        long long t = t0 + j * 256 + thr;
        if (t >= N_TRI) continue;
        unsigned int mij = mij_r[j];
        int c = mij >> 22;
        int slot = lbase[c] + slot_r[j];
        if (slot < cap) {
            int2 e;
            e.x = (int)(mij & 0x3FFFFF);   // a5:5 | lidx:17
            e.y = qik_r[j];
            cbucket[(size_t)(c * NSUB + sub) * cap + slot] = e;
        } else {
            int o = atomicAdd(&ccnt[OVF_CNT_IDX], 1);
            if (o < OVF_CAP) { int2 e; e.x = (int)mij; e.y = qik_r[j]; ovf[o] = e; }
        }
    }
}

// one block per (coarse bucket, half): 4 sub-segments flattened into one
// software-pipelined loop (~8.3 iters/thread). Window staged once; ij-valid
// tracked as LDS flag bits; ik side = 1 random line (geometry + colocated max).
__global__ __launch_bounds__(256) void reduce4(
    const int* __restrict__ ccnt, const int2* __restrict__ cbucket, int cap,
    float4* __restrict__ packs, const int* __restrict__ pbase,
    unsigned int* __restrict__ flagbits, float* __restrict__ out)
{
    __shared__ float4 win[WCAP];
    __shared__ float lacc[APB * 17];      // +1 pad per atom row
    __shared__ unsigned int lflag[WCAP / 32];
    const int blk = blockIdx.x;
    const int b = blk >> 1;               // coarse bucket
    const int half = blk & 1;
    const int thr = threadIdx.x;
    const int base = pbase[b];
    const int wlen = min(pbase[b + 1] - base, WCAP);

    for (int i = thr; i < APB * 17; i += 256) lacc[i] = 0.0f;
    if (thr < WCAP / 32) lflag[thr] = 0u;
    for (int i = thr; i < wlen; i += 256) win[i] = packs[base + i];

    const int seg0 = b * NSUB + half * MERGE;
    int n0 = min(ccnt[seg0 + 0], cap);
    int n1 = min(ccnt[seg0 + 1], cap);
    int n2 = min(ccnt[seg0 + 2], cap);
    int n3 = min(ccnt[seg0 + 3], cap);
    int c1 = n0, c2 = n0 + n1, c3 = n0 + n1 + n2;
    int m = c3 + n3;
    const int2* segp0 = cbucket + (size_t)seg0 * cap;
    int* pw = (int*)packs;
    __syncthreads();

#define FETCH_E(jj, dst) { \
        int s2_ = (jj >= c1) + (jj >= c2) + (jj >= c3); \
        int o_ = jj - (s2_ == 0 ? 0 : (s2_ == 1 ? c1 : (s2_ == 2 ? c2 : c3))); \
        dst = segp0[(size_t)s2_ * cap + o_]; }

    int j = thr;
    int2 e = make_int2(0, 0);
    float4 B = make_float4(0.f, 0.f, 0.f, 0.f);
    if (j < m) { FETCH_E(j, e); B = packs[e.y]; }
    while (j < m) {
        int jn = j + 256;
        int2 en = make_int2(0, 0);
        float4 Bn = B;
        if (jn < m) { FETCH_E(jn, en); Bn = packs[en.y]; }   // prefetch next
        int lidx = e.x & 0x1FFFF;
        int a5 = (e.x >> 17) & (APB - 1);
        float4 A = (lidx < WCAP) ? win[lidx] : packs[base + lidx];
        float A8[8], R2;
        if (tri_math(A, B, A8, R2)) {
            if (lidx < WCAP) {
                atomicOr(&lflag[lidx >> 5], 1u << (lidx & 31));
            } else {
                int g = base + lidx;
                atomicOr(&flagbits[g >> 5], 1u << (g & 31));
            }
            atomicMax(&pw[4 * e.y + 3], (b << ASH) + a5);    // ik side
#pragma unroll
            for (int s = 0; s < 16; ++s)
                atomicAdd(&lacc[a5 * 17 + s], A8[s & 7] * __expf(-c_eta[s] * R2));
        }
        j = jn; e = en; B = Bn;
    }
#undef FETCH_E
    __syncthreads();

    // merge ij-valid flags (unaligned window base → shift into global words)
    {
        int sh = base & 31;
        int w0 = base >> 5;
        int nw = (wlen + 31) >> 5;
        for (int i = thr; i < nw; i += 256) {
            unsigned int w = lflag[i];
            if (!w) continue;
            atomicOr(&flagbits[w0 + i], w << sh);
            if (sh) {
                unsigned int hi = w >> (32 - sh);
                if (hi) atomicOr(&flagbits[w0 + i + 1], hi);
            }
        }
    }
    // merge fingerprint accumulators
    for (int t = thr; t < APB * N_SF; t += 256) {
        int atom = (b << ASH) + (t >> 4);
        float v = lacc[(t >> 4) * 17 + (t & 15)];
        if (atom < N_ATOM && v != 0.0f)
            unsafeAtomicAdd(out + (size_t)atom * N_SF + (t & 15), v);
    }
}

// exact path for bucket-overflow triplets (order-free vs reduce4)
__global__ __launch_bounds__(256) void ovf3(
    const int* __restrict__ ccnt, const int2* __restrict__ ovf,
    float4* __restrict__ packs, const int* __restrict__ pbase,
    unsigned int* __restrict__ flagbits, float* __restrict__ out)
{
    int i = blockIdx.x * blockDim.x + threadIdx.x;
    int n = ccnt[OVF_CNT_IDX];
    if (n > OVF_CAP) n = OVF_CAP;
    if (i >= n) return;
    int2 e = ovf[i];
    unsigned int mij = (unsigned int)e.x;
    int qik = e.y;
    int c = mij >> 22;
    int a5 = (mij >> 17) & (APB - 1);
    int lidx = mij & 0x1FFFF;
    int qij = pbase[c] + lidx;
    float4 A = packs[qij];
    float4 B = packs[qik];
    float A8[8], R2;
    if (!tri_math(A, B, A8, R2)) return;
    int atom = (c << ASH) + a5;
    int* pw = (int*)packs;
    atomicOr(&flagbits[qij >> 5], 1u << (qij & 31));
    atomicMax(&pw[4 * qik + 3], atom);
    float* basep = out + (size_t)atom * N_SF;
#pragma unroll
    for (int s = 0; s < 16; ++s)
        unsafeAtomicAdd(basep + s, A8[s & 7] * __expf(-c_eta[s] * R2));
}

__global__ __launch_bounds__(256) void fin3(
    const unsigned int* __restrict__ amap, const int* __restrict__ pbase,
    const float4* __restrict__ packs, const unsigned int* __restrict__ flagbits,
    float* __restrict__ out)
{
    int p = blockIdx.x * blockDim.x + threadIdx.x;
    if (p >= N_PAIR) return;
    unsigned int mm = amap[p];
    int c = mm >> 22;
    int lidx = (int)(mm & 0x1FFFF);
    int a5 = (mm >> 17) & (APB - 1);
    int q = pbase[c] + lidx;
    int w = ((const int*)packs)[4 * q + 3];
    unsigned int fb = flagbits[q >> 5];
    int a = (c << ASH) + a5;
    int v = ((fb >> (q & 31)) & 1u) ? max(w, a) : w;
    float* jf = out + FP_ELEMS;
    jf[2 * p + 0] = (float)p;
    jf[2 * p + 1] = (float)v;
}

// ---------------------------------------------------------------------------
// legacy fallback
// ---------------------------------------------------------------------------

__global__ __launch_bounds__(256) void init_legacy(float* __restrict__ out) {
    int i = blockIdx.x * blockDim.x + threadIdx.x;
    if (i < FP_ELEMS) out[i] = 0.0f;
    if (i < N_PAIR) ((int*)out + FP_ELEMS)[2 * i + 1] = -1;
}

__global__ __launch_bounds__(256) void tri_legacy(
    const int* __restrict__ ind2, const int2* __restrict__ ind3,
    const float* __restrict__ dist, const float* __restrict__ diff,
    const float* __restrict__ fc, float* __restrict__ out) {
    int t = blockIdx.x * blockDim.x + threadIdx.x;
    if (t >= N_TRI) return;
    int2 pr = ind3[t];
    int ij = pr.x, ik = pr.y;
    float4 A, B;
    A.x = diff[3 * ij + 0]; A.y = diff[3 * ij + 1]; A.z = diff[3 * ij + 2]; A.w = 0.f;
    B.x = diff[3 * ik + 0]; B.y = diff[3 * ik + 1]; B.z = diff[3 * ik + 2]; B.w = 0.f;
    float A8[8], R2;
    if (!tri_math(A, B, A8, R2)) return;
    int atom = ind2[2 * ij];
    int* jac = (int*)out + FP_ELEMS;
    atomicMax(&jac[2 * ij + 1], atom);
    atomicMax(&jac[2 * ik + 1], atom);
    float* base = out + (size_t)atom * N_SF;
#pragma unroll
    for (int s = 0; s < 16; ++s)
        unsafeAtomicAdd(base + s, A8[s & 7] * __expf(-c_eta[s] * R2));
}

__global__ __launch_bounds__(256) void fin_legacy(float* __restrict__ out) {
    int p = blockIdx.x * blockDim.x + threadIdx.x;
    if (p >= N_PAIR) return;
    int* jac = (int*)out + FP_ELEMS;
    int v = jac[2 * p + 1];
    float* jf = (float*)jac;
    jf[2 * p + 0] = (float)p;
    jf[2 * p + 1] = (float)v;
}

// ---------------------------------------------------------------------------

extern "C" void kernel_launch(void* const* d_in, const int* in_sizes, int n_in,
                              void* d_out, int out_size, void* d_ws, size_t ws_size,
                              hipStream_t stream) {
    const int2*  ind2 = (const int2*)d_in[0];
    const int2*  ind3 = (const int2*)d_in[1];
    const float* dist = (const float*)d_in[2];
    const float* diff = (const float*)d_in[3];
    const float* fc   = (const float*)d_in[5];
    float* out = (float*)d_out;

    const size_t seg_stride = (size_t)NSEG * sizeof(int2);
    const size_t need_min = OFF_CB + seg_stride * 608;

    if (ws_size >= need_min) {
        char* ws = (char*)d_ws;
        int* ccnt            = (int*)(ws + OFF_CCNT);
        int* pcnt            = (int*)(ws + OFF_PCNT);
        int* pplace          = (int*)(ws + OFF_PPLACE);
        int* pbase           = (int*)(ws + OFF_PBASE);
        unsigned int* amap   = (unsigned int*)(ws + OFF_AMAP);
        unsigned int* flagb  = (unsigned int*)(ws + OFF_FLAGB);
        int2* ovf            = (int2*)(ws + OFF_OVF);
        float4* packs        = (float4*)(ws + OFF_PACKS);
        int2* cbucket        = (int2*)(ws + OFF_CB);
        int cap = (int)((ws_size - OFF_CB) / seg_stride);
        if (cap > 1024) cap = 1024;

        int pb = (N_PAIR + 255) / 256;
        zero_meta<<<(ZERO_INTS + 255) / 256, 256, 0, stream>>>((int*)ws, flagb);
        pair_hist<<<240, 256, 0, stream>>>(ind2, pcnt);
        scan_bases<<<1, 1024, 0, stream>>>(pcnt, pbase);
        pair_place<<<pb, 256, 0, stream>>>(ind2, diff, pbase, pplace, amap, packs, out);
        bin3<<<NTILES, 256, 0, stream>>>(ind3, amap, pbase, ccnt, cbucket, ovf, cap);
        reduce4<<<NRB, 256, 0, stream>>>(ccnt, cbucket, cap, packs, pbase, flagb, out);
        ovf3<<<OVF_CAP / 256, 256, 0, stream>>>(ccnt, ovf, packs, pbase, flagb, out);
        fin3<<<pb, 256, 0, stream>>>(amap, pbase, packs, flagb, out);
    } else {
        init_legacy<<<(N_PAIR + 255) / 256, 256, 0, stream>>>(out);
        tri_legacy<<<(N_TRI + 255) / 256, 256, 0, stream>>>((const int*)d_in[0], ind3, dist, diff, fc, out);
        fin_legacy<<<(N_PAIR + 255) / 256, 256, 0, stream>>>(out);
    }
    (void)dist; (void)fc; (void)in_sizes; (void)n_in; (void)out_size;
}

// Round 3
// 526.638 us; speedup vs baseline: 1.0483x; 1.0483x over previous
//
#include <hip/hip_runtime.h>

#define N_ATOM 30000
#define N_PAIR 1000000
#define N_TRI  4000000
#define N_SF   16
#define FP_ELEMS (N_ATOM * N_SF)

#define ASH  5                      // atoms per coarse bucket = 32
#define APB  32
#define NCB  938                    // ceil(30000/32)
#define NSUB 8                      // XCD sub-buckets (bin3 scatter spreading)
#define NSEG (NCB * NSUB)           // 7504
#define OVF_CNT_IDX NSEG
#define OVF_CAP 131072
#define TILE 4096
#define PER_TH 16
#define NTILES ((N_TRI + TILE - 1) / TILE)   // 977
#define MERGE 2                     // subs merged per reduce4 block
#define NRB (NCB * 4)               // reduce4 grid: 3752, ~1066 triplets each
#define LFB 2048                    // LDS ij-flag bitset (bits)

// workspace layout (bytes)
// [0, 167936) zeroed by zero_meta (ccnt + pcnt + pplace + pbase); flagbits too
#define OFF_CCNT   0ULL             // (NSEG+1) ints (reserve 32 KiB)
#define OFF_PCNT   32768ULL         // 938 counters, padded stride 16 ints
#define OFF_PPLACE 98304ULL         // 938 counters, padded stride 16 ints
#define OFF_PBASE  163840ULL        // 939 ints (exclusive bases + sentinel)
#define OFF_AMAP   196608ULL        // 4,000,000 B: per-pair {c:10|a5:5|lidx:17}
#define OFF_FLAGB  4196608ULL       // 131,072 B: ij-valid bit per permuted pair
#define OFF_OVF    4327680ULL       // 1,048,576 B: int2 * 131072
#define OFF_PACKS  5376256ULL       // 16,000,000 B: float4 {dx,dy,dz, bitcast(ikmax)}
#define OFF_CB     21376256ULL      // cbucket: NSEG * cap * 8
#define ZERO_INTS  41984            // 167,936 / 4
#define FLAGB_INTS 32768

__device__ __constant__ float c_eta[16] = {
    0.01f, 0.014f, 0.02f, 0.028f, 0.04f, 0.056f, 0.08f, 0.11f,
    0.16f, 0.22f, 0.32f, 0.45f, 0.63f, 0.72f, 0.9f, 1.0f};

// ---------------------------------------------------------------------------
// geometry math; fc recomputed from distances (pack.w carries the ik max)
__device__ __forceinline__ bool tri_math(
    float4 A, float4 B, float A8[8], float& R2)
{
    float ax = A.x, ay = A.y, az = A.z;
    float bx = B.x, by = B.y, bz = B.z;
    float d2ij = fmaf(ax, ax, fmaf(ay, ay, az * az));
    float d2ik = fmaf(bx, bx, fmaf(by, by, bz * bz));
    float jx = bx - ax, jy = by - ay, jz = bz - az;
    float d2jk = fmaf(jx, jx, fmaf(jy, jy, jz * jz));
    if (!(d2jk < 36.0f)) return false;
    float dij = sqrtf(d2ij);
    float dik = sqrtf(d2ik);
    float djk = sqrtf(d2jk);
    const float PI_OVER_RC = 0.5235987755982988f;
    float fcij = 0.5f * (__cosf(PI_OVER_RC * dij) + 1.0f);
    float fcik = 0.5f * (__cosf(PI_OVER_RC * dik) + 1.0f);
    float fcjk = 0.5f * (__cosf(PI_OVER_RC * djk) + 1.0f);
    float dot = fmaf(ax, bx, fmaf(ay, by, az * bz));
    float cosv = dot / (dij * dik);
    R2 = d2ij + d2ik + d2jk;
    float FCt = fcij * fcik * fcjk;
    float bm = fmaxf(1.0f - cosv, 0.0f);
    float bp = fmaxf(1.0f + cosv, 0.0f);
    float bm2 = bm * bm, bp2 = bp * bp;
    float bm4 = bm2 * bm2, bp4 = bp2 * bp2;
    float bm8 = bm4 * bm4, bp8 = bp4 * bp4;
    A8[0] = FCt * bm;               A8[1] = FCt * bp;
    A8[2] = 0.5f * FCt * bm2;       A8[3] = 0.5f * FCt * bp2;
    A8[4] = 0.125f * FCt * bm4;     A8[5] = 0.125f * FCt * bp4;
    A8[6] = 0.0078125f * FCt * bm8; A8[7] = 0.0078125f * FCt * bp8;
    return true;
}

// ---------------------------------------------------------------------------
// fast path
// ---------------------------------------------------------------------------

__global__ __launch_bounds__(256) void zero_meta(
    int* __restrict__ m, unsigned int* __restrict__ fb)
{
    int i = blockIdx.x * blockDim.x + threadIdx.x;
    if (i < ZERO_INTS) m[i] = 0;
    if (i < FLAGB_INTS) fb[i] = 0u;
}

// histogram pairs per coarse bucket (LDS-staged; padded global counters)
__global__ __launch_bounds__(256) void pair_hist(
    const int2* __restrict__ ind2, int* __restrict__ pcnt)
{
    __shared__ int h[NCB];
    for (int i = threadIdx.x; i < NCB; i += 256) h[i] = 0;
    __syncthreads();
    int stride = gridDim.x * 256;
    for (int p = blockIdx.x * 256 + threadIdx.x; p < N_PAIR; p += stride)
        atomicAdd(&h[ind2[p].x >> ASH], 1);
    __syncthreads();
    for (int i = threadIdx.x; i < NCB; i += 256) {
        int v = h[i];
        if (v) atomicAdd(&pcnt[i * 16], v);
    }
}

// exclusive prefix scan of the 938 bucket counts (single 1024-thread block)
__global__ __launch_bounds__(1024) void scan_bases(
    const int* __restrict__ pcnt, int* __restrict__ pbase)
{
    __shared__ int s[1024];
    int t = threadIdx.x;
    int v0 = (t < NCB) ? pcnt[t * 16] : 0;
    s[t] = v0;
    __syncthreads();
    for (int off = 1; off < 1024; off <<= 1) {
        int v = 0;
        if (t >= off) v = s[t - off];
        __syncthreads();
        s[t] += v;
        __syncthreads();
    }
    if (t < NCB) pbase[t] = s[t] - v0;     // exclusive
    if (t == 0) pbase[NCB] = N_PAIR;       // sentinel
}

// place pairs into bucket-permuted packs[] (w = bitcast(-1) running max);
// build amap; also zero the fp output rows
__global__ __launch_bounds__(256) void pair_place(
    const int2* __restrict__ ind2, const float* __restrict__ diff,
    const int* __restrict__ pbase, int* __restrict__ pplace,
    unsigned int* __restrict__ amap, float4* __restrict__ packs,
    float* __restrict__ out)
{
    int p = blockIdx.x * blockDim.x + threadIdx.x;
    if (p < FP_ELEMS) out[p] = 0.0f;
    if (p >= N_PAIR) return;
    int a = ind2[p].x;
    int c = a >> ASH;
    int l = atomicAdd(&pplace[c * 16], 1);
    int q = pbase[c] + l;
    amap[p] = ((unsigned)c << 22) | ((unsigned)(a & (APB - 1)) << 17) | (unsigned)l;
    float4 r;
    r.x = diff[3 * p + 0];
    r.y = diff[3 * p + 1];
    r.z = diff[3 * p + 2];
    r.w = __int_as_float(-1);
    packs[q] = r;
}

// LDS-staged counting scatter into coarse buckets (XCD sub-bucketed).
// Entries carry {a5,lidx} for the ij side and the permuted index q for ik.
__global__ __launch_bounds__(256) void bin3(
    const int2* __restrict__ ind3, const unsigned int* __restrict__ amap,
    const int* __restrict__ pbase,
    int* __restrict__ ccnt, int2* __restrict__ cbucket,
    int2* __restrict__ ovf, int cap)
{
    __shared__ int lcnt[NCB];
    __shared__ int lbase[NCB];
    const int thr = threadIdx.x;
    const int sub = blockIdx.x & (NSUB - 1);
    const long long t0 = (long long)blockIdx.x * TILE;

    for (int i = thr; i < NCB; i += 256) lcnt[i] = 0;
    __syncthreads();

    unsigned int mij_r[PER_TH];
    int qik_r[PER_TH];
    int slot_r[PER_TH];
#pragma unroll
    for (int j = 0; j < PER_TH; ++j) {
        long long t = t0 + j * 256 + thr;
        unsigned int mij = 0; int qik = 0, s = -1;
        if (t < N_TRI) {
            int2 pr = ind3[t];
            mij = amap[pr.x];
            unsigned int mik = amap[pr.y];
            qik = pbase[mik >> 22] + (int)(mik & 0x1FFFF);
            s = atomicAdd(&lcnt[mij >> 22], 1);
        }
        mij_r[j] = mij; qik_r[j] = qik; slot_r[j] = s;
    }
    __syncthreads();
    for (int c = thr; c < NCB; c += 256) {
        int n = lcnt[c];
        lbase[c] = n ? atomicAdd(&ccnt[c * NSUB + sub], n) : 0;
    }
    __syncthreads();
#pragma unroll
    for (int j = 0; j < PER_TH; ++j) {
        long long t = t0 + j * 256 + thr;
        if (t >= N_TRI) continue;
        unsigned int mij = mij_r[j];
        int c = mij >> 22;
        int slot = lbase[c] + slot_r[j];
        if (slot < cap) {
            int2 e;
            e.x = (int)(mij & 0x3FFFFF);   // a5:5 | lidx:17
            e.y = qik_r[j];
            cbucket[(size_t)(c * NSUB + sub) * cap + slot] = e;
        } else {
            int o = atomicAdd(&ccnt[OVF_CNT_IDX], 1);
            if (o < OVF_CAP) { int2 e; e.x = (int)mij; e.y = qik_r[j]; ovf[o] = e; }
        }
    }
}

// one block per (bucket, quad): 2 sub-segments, ~1066 triplets, ~4.2/thread.
// No LDS window (permuted packs window is L1/L2-hot by construction); tiny
// LDS (lacc + flag bitset) -> wave-cap occupancy; depth-2 load batching for
// ILP. ik side = 1 random line (geometry + colocated atomicMax word).
__global__ __launch_bounds__(256) void reduce4(
    const int* __restrict__ ccnt, const int2* __restrict__ cbucket, int cap,
    float4* __restrict__ packs, const int* __restrict__ pbase,
    unsigned int* __restrict__ flagbits, float* __restrict__ out)
{
    __shared__ float lacc[APB * 17];      // +1 pad per atom row
    __shared__ unsigned int lflag[LFB / 32];
    const int blk = blockIdx.x;
    const int b = blk >> 2;               // coarse bucket
    const int quad = blk & 3;
    const int thr = threadIdx.x;
    const int base = pbase[b];
    const int wlen = pbase[b + 1] - base;

    for (int i = thr; i < APB * 17; i += 256) lacc[i] = 0.0f;
    if (thr < LFB / 32) lflag[thr] = 0u;

    const int seg0 = b * NSUB + quad * MERGE;
    const int n0 = min(ccnt[seg0 + 0], cap);
    const int n1 = min(ccnt[seg0 + 1], cap);
    const int m = n0 + n1;
    const int2* segp0 = cbucket + (size_t)seg0 * cap;
    int* pw = (int*)packs;
    __syncthreads();

    for (int j0 = 0; j0 < m; j0 += 512) {
        int i1 = j0 + thr;
        int i2 = i1 + 256;
        bool v1 = i1 < m, v2 = i2 < m;
        int jc1 = v1 ? i1 : m - 1;        // clamped (m>0 inside loop)
        int jc2 = v2 ? i2 : m - 1;
        int s1 = jc1 >= n0, s2 = jc2 >= n0;
        int2 e1 = segp0[(size_t)s1 * cap + (jc1 - (s1 ? n0 : 0))];
        int2 e2 = segp0[(size_t)s2 * cap + (jc2 - (s2 ? n0 : 0))];
        int l1 = e1.x & 0x1FFFF;
        int l2 = e2.x & 0x1FFFF;
        float4 B1 = packs[e1.y];          // independent random loads, both in
        float4 B2 = packs[e2.y];          // flight before any use
        float4 A1 = packs[base + l1];     // L2-hot window reads
        float4 A2 = packs[base + l2];

        float A8[8], R2v;
        if (v1 && tri_math(A1, B1, A8, R2v)) {
            int a5 = (e1.x >> 17) & (APB - 1);
            if (l1 < LFB) atomicOr(&lflag[l1 >> 5], 1u << (l1 & 31));
            else { int g = base + l1; atomicOr(&flagbits[g >> 5], 1u << (g & 31)); }
            atomicMax(&pw[4 * e1.y + 3], (b << ASH) + a5);
#pragma unroll
            for (int s = 0; s < 16; ++s)
                atomicAdd(&lacc[a5 * 17 + s], A8[s & 7] * __expf(-c_eta[s] * R2v));
        }
        if (v2 && tri_math(A2, B2, A8, R2v)) {
            int a5 = (e2.x >> 17) & (APB - 1);
            if (l2 < LFB) atomicOr(&lflag[l2 >> 5], 1u << (l2 & 31));
            else { int g = base + l2; atomicOr(&flagbits[g >> 5], 1u << (g & 31)); }
            atomicMax(&pw[4 * e2.y + 3], (b << ASH) + a5);
#pragma unroll
            for (int s = 0; s < 16; ++s)
                atomicAdd(&lacc[a5 * 17 + s], A8[s & 7] * __expf(-c_eta[s] * R2v));
        }
    }
    __syncthreads();

    // merge ij-valid flags (unaligned window base -> shift into global words)
    {
        int sh = base & 31;
        int w0 = base >> 5;
        int nw = (min(wlen, LFB) + 31) >> 5;
        for (int i = thr; i < nw; i += 256) {
            unsigned int w = lflag[i];
            if (!w) continue;
            atomicOr(&flagbits[w0 + i], w << sh);
            if (sh) {
                unsigned int hi = w >> (32 - sh);
                if (hi) atomicOr(&flagbits[w0 + i + 1], hi);
            }
        }
    }
    // merge fingerprint accumulators
    for (int t = thr; t < APB * N_SF; t += 256) {
        int atom = (b << ASH) + (t >> 4);
        float v = lacc[(t >> 4) * 17 + (t & 15)];
        if (atom < N_ATOM && v != 0.0f)
            unsafeAtomicAdd(out + (size_t)atom * N_SF + (t & 15), v);
    }
}

// exact path for bucket-overflow triplets (order-free vs reduce4)
__global__ __launch_bounds__(256) void ovf3(
    const int* __restrict__ ccnt, const int2* __restrict__ ovf,
    float4* __restrict__ packs, const int* __restrict__ pbase,
    unsigned int* __restrict__ flagbits, float* __restrict__ out)
{
    int i = blockIdx.x * blockDim.x + threadIdx.x;
    int n = ccnt[OVF_CNT_IDX];
    if (n > OVF_CAP) n = OVF_CAP;
    if (i >= n) return;
    int2 e = ovf[i];
    unsigned int mij = (unsigned int)e.x;
    int qik = e.y;
    int c = mij >> 22;
    int a5 = (mij >> 17) & (APB - 1);
    int lidx = mij & 0x1FFFF;
    int qij = pbase[c] + lidx;
    float4 A = packs[qij];
    float4 B = packs[qik];
    float A8[8], R2;
    if (!tri_math(A, B, A8, R2)) return;
    int atom = (c << ASH) + a5;
    int* pw = (int*)packs;
    atomicOr(&flagbits[qij >> 5], 1u << (qij & 31));
    atomicMax(&pw[4 * qik + 3], atom);
    float* basep = out + (size_t)atom * N_SF;
#pragma unroll
    for (int s = 0; s < 16; ++s)
        unsafeAtomicAdd(basep + s, A8[s & 7] * __expf(-c_eta[s] * R2));
}

__global__ __launch_bounds__(256) void fin3(
    const unsigned int* __restrict__ amap, const int* __restrict__ pbase,
    const float4* __restrict__ packs, const unsigned int* __restrict__ flagbits,
    float* __restrict__ out)
{
    int p = blockIdx.x * blockDim.x + threadIdx.x;
    if (p >= N_PAIR) return;
    unsigned int mm = amap[p];
    int c = mm >> 22;
    int lidx = (int)(mm & 0x1FFFF);
    int a5 = (mm >> 17) & (APB - 1);
    int q = pbase[c] + lidx;
    int w = ((const int*)packs)[4 * q + 3];
    unsigned int fb = flagbits[q >> 5];
    int a = (c << ASH) + a5;
    int v = ((fb >> (q & 31)) & 1u) ? max(w, a) : w;
    float* jf = out + FP_ELEMS;
    jf[2 * p + 0] = (float)p;
    jf[2 * p + 1] = (float)v;
}

// ---------------------------------------------------------------------------
// legacy fallback
// ---------------------------------------------------------------------------

__global__ __launch_bounds__(256) void init_legacy(float* __restrict__ out) {
    int i = blockIdx.x * blockDim.x + threadIdx.x;
    if (i < FP_ELEMS) out[i] = 0.0f;
    if (i < N_PAIR) ((int*)out + FP_ELEMS)[2 * i + 1] = -1;
}

__global__ __launch_bounds__(256) void tri_legacy(
    const int* __restrict__ ind2, const int2* __restrict__ ind3,
    const float* __restrict__ dist, const float* __restrict__ diff,
    const float* __restrict__ fc, float* __restrict__ out) {
    int t = blockIdx.x * blockDim.x + threadIdx.x;
    if (t >= N_TRI) return;
    int2 pr = ind3[t];
    int ij = pr.x, ik = pr.y;
    float4 A, B;
    A.x = diff[3 * ij + 0]; A.y = diff[3 * ij + 1]; A.z = diff[3 * ij + 2]; A.w = 0.f;
    B.x = diff[3 * ik + 0]; B.y = diff[3 * ik + 1]; B.z = diff[3 * ik + 2]; B.w = 0.f;
    float A8[8], R2;
    if (!tri_math(A, B, A8, R2)) return;
    int atom = ind2[2 * ij];
    int* jac = (int*)out + FP_ELEMS;
    atomicMax(&jac[2 * ij + 1], atom);
    atomicMax(&jac[2 * ik + 1], atom);
    float* base = out + (size_t)atom * N_SF;
#pragma unroll
    for (int s = 0; s < 16; ++s)
        unsafeAtomicAdd(base + s, A8[s & 7] * __expf(-c_eta[s] * R2));
}

__global__ __launch_bounds__(256) void fin_legacy(float* __restrict__ out) {
    int p = blockIdx.x * blockDim.x + threadIdx.x;
    if (p >= N_PAIR) return;
    int* jac = (int*)out + FP_ELEMS;
    int v = jac[2 * p + 1];
    float* jf = (float*)jac;
    jf[2 * p + 0] = (float)p;
    jf[2 * p + 1] = (float)v;
}

// ---------------------------------------------------------------------------

extern "C" void kernel_launch(void* const* d_in, const int* in_sizes, int n_in,
                              void* d_out, int out_size, void* d_ws, size_t ws_size,
                              hipStream_t stream) {
    const int2*  ind2 = (const int2*)d_in[0];
    const int2*  ind3 = (const int2*)d_in[1];
    const float* dist = (const float*)d_in[2];
    const float* diff = (const float*)d_in[3];
    const float* fc   = (const float*)d_in[5];
    float* out = (float*)d_out;

    const size_t seg_stride = (size_t)NSEG * sizeof(int2);
    const size_t need_min = OFF_CB + seg_stride * 608;

    if (ws_size >= need_min) {
        char* ws = (char*)d_ws;
        int* ccnt            = (int*)(ws + OFF_CCNT);
        int* pcnt            = (int*)(ws + OFF_PCNT);
        int* pplace          = (int*)(ws + OFF_PPLACE);
        int* pbase           = (int*)(ws + OFF_PBASE);
        unsigned int* amap   = (unsigned int*)(ws + OFF_AMAP);
        unsigned int* flagb  = (unsigned int*)(ws + OFF_FLAGB);
        int2* ovf            = (int2*)(ws + OFF_OVF);
        float4* packs        = (float4*)(ws + OFF_PACKS);
        int2* cbucket        = (int2*)(ws + OFF_CB);
        int cap = (int)((ws_size - OFF_CB) / seg_stride);
        if (cap > 1024) cap = 1024;

        int pb = (N_PAIR + 255) / 256;
        zero_meta<<<(ZERO_INTS + 255) / 256, 256, 0, stream>>>((int*)ws, flagb);
        pair_hist<<<240, 256, 0, stream>>>(ind2, pcnt);
        scan_bases<<<1, 1024, 0, stream>>>(pcnt, pbase);
        pair_place<<<pb, 256, 0, stream>>>(ind2, diff, pbase, pplace, amap, packs, out);
        bin3<<<NTILES, 256, 0, stream>>>(ind3, amap, pbase, ccnt, cbucket, ovf, cap);
        reduce4<<<NRB, 256, 0, stream>>>(ccnt, cbucket, cap, packs, pbase, flagb, out);
        ovf3<<<OVF_CAP / 256, 256, 0, stream>>>(ccnt, ovf, packs, pbase, flagb, out);
        fin3<<<pb, 256, 0, stream>>>(amap, pbase, packs, flagb, out);
    } else {
        init_legacy<<<(N_PAIR + 255) / 256, 256, 0, stream>>>(out);
        tri_legacy<<<(N_TRI + 255) / 256, 256, 0, stream>>>((const int*)d_in[0], ind3, dist, diff, fc, out);
        fin_legacy<<<(N_PAIR + 255) / 256, 256, 0, stream>>>(out);
    }
    (void)dist; (void)fc; (void)in_sizes; (void)n_in; (void)out_size;
}